// Round 1
// baseline (1143.605 us; speedup 1.0000x reference)
//
#include <hip/hip_runtime.h>

// Problem constants (from reference): B=16, H=180, W=240, N=8M events of 5 floats.
constexpr int NB   = 16;
constexpr int NH   = 180;
constexpr int NW   = 240;
constexpr int FULL = NB * NH * NW;                 // 691200 full-res cells
constexpr int SEG  = (NH / 2) * (NW / 2);          // 10800 half-res cells per batch
constexpr int HALF = NB * SEG;                     // 172800 half-res cells

// ws layout (4-byte elements):
//   [0, 16)                     tmax per batch (float bits as uint, atomicMax)
//   [16, 16+FULL)               cont: int32 full-res histogram
//   [16+FULL, +HALF)            cnt:  int32 half-res histogram
//   next HALF                   tsum: float, raw-t sums (events whose own batch owns the voxel)
//   next HALF                   bleed: float, raw-t sums from batch b-1 events that bled into
//                               batch b's segment (y=179, x>=120 quirk of the float floordiv idx)
constexpr int WS_ELEMS = 16 + FULL + 3 * HALF;     // ~4.84 MB

__global__ __launch_bounds__(256) void k_init(unsigned int* __restrict__ ws) {
    int i = blockIdx.x * blockDim.x + threadIdx.x;
    int stride = gridDim.x * blockDim.x;
    for (; i < WS_ELEMS; i += stride) ws[i] = 0u;
}

__global__ __launch_bounds__(256) void k_events(const float* __restrict__ ev, int n,
                                                unsigned int* __restrict__ tmaxb,
                                                int* __restrict__ cont,
                                                int* __restrict__ cnt,
                                                float* __restrict__ tsum,
                                                float* __restrict__ bleed) {
    __shared__ unsigned int smax[NB];
    if (threadIdx.x < NB) smax[threadIdx.x] = 0u;
    __syncthreads();

    // contiguous chunk per block: coalesced reads, and since b is sorted each
    // block/wave sees (almost always) a single batch -> cheap tmax reduction +
    // good L2 locality on the histogram atomics.
    int chunk = (n + gridDim.x - 1) / (int)gridDim.x;
    int start = blockIdx.x * chunk;
    int end   = min(start + chunk, n);

    for (int i = start + (int)threadIdx.x; i < end; i += (int)blockDim.x) {
        const float* r = ev + (size_t)5 * (size_t)i;
        float x = r[0];
        float y = r[1];
        float t = r[2];
        // r[3] (polarity) is unused downstream in the reference
        float b = r[4];
        int xi = (int)x, yi = (int)y, bi = (int)b;

        // --- per-batch tmax (t >= 0 so uint-bit max == float max) ---
        unsigned long long active = __ballot(1);
        int bf = __builtin_amdgcn_readfirstlane(bi);
        if (active == ~0ull && __all(bi == bf)) {
            float m = t;
#pragma unroll
            for (int o = 32; o > 0; o >>= 1) m = fmaxf(m, __shfl_xor(m, o));
            if ((threadIdx.x & 63) == 0) atomicMax(&smax[bf], __float_as_uint(m));
        } else {
            atomicMax(&smax[bi], __float_as_uint(t));
        }

        // --- full-res histogram: idx = x + W*y + W*H*b (always in-bounds) ---
        int ic = xi + NW * yi + NW * NH * bi;
        atomicAdd(&cont[ic], 1);

        // --- half-res: idx = x//2 + (W*y)//4 + (W*H*b)//4 = (x>>1) + 60y + 10800b ---
        int loc = (xi >> 1) + (NW / 4) * yi;   // can reach 10859 >= SEG (y=179, x>=120)
        int ik  = loc + SEG * bi;
        if (ik < HALF) {                       // replicate jax mode="drop"
            atomicAdd(&cnt[ik], 1);
            if (loc >= SEG) atomicAdd(&bleed[ik], t);  // lands in batch bi+1's segment
            else            atomicAdd(&tsum[ik], t);
        }
    }

    __syncthreads();
    if (threadIdx.x < NB) {
        unsigned v = smax[threadIdx.x];
        if (v) atomicMax(&tmaxb[threadIdx.x], v);
    }
}

__global__ __launch_bounds__(256) void k_epilogue(const unsigned int* __restrict__ tmaxb,
                                                  const int* __restrict__ cont,
                                                  const int* __restrict__ cnt,
                                                  const float* __restrict__ tsum,
                                                  const float* __restrict__ bleed,
                                                  float* __restrict__ out) {
    int v = blockIdx.x * blockDim.x + threadIdx.x;   // half-res cell index
    if (v >= HALF) return;
    int b   = v / SEG;
    int rem = v - b * SEG;
    int i   = rem / (NW / 2);
    int j   = rem - i * (NW / 2);

    float* out_cont = out;
    float* out_cnt  = out + FULL;
    float* out_tim  = out + FULL + HALF;
    float* out_dx   = out + FULL + 2 * HALF;
    float* out_dy   = out + FULL + 3 * HALF;

    // 2x2 full-res block owned by this half-res cell
    int cbase = b * (NH * NW) + (2 * i) * NW + 2 * j;
    int c00 = cont[cbase],      c01 = cont[cbase + 1];
    int c10 = cont[cbase + NW], c11 = cont[cbase + NW + 1];

    out_cont[cbase]          = (float)c00;
    out_cont[cbase + 1]      = (float)c01;
    out_cont[cbase + NW]     = (float)c10;
    out_cont[cbase + NW + 1] = (float)c11;

    int c = cnt[v];
    out_cnt[v] = (float)c;

    // timer: events normalized by their OWN batch tmax; bleed voxels received
    // events from batch b-1 (the floordiv overflow), normalized by tmax[b-1].
    float tm   = __uint_as_float(tmaxb[b]);
    float tmp  = (b > 0) ? __uint_as_float(tmaxb[b - 1]) : 1.0f;  // bleed[v]==0 when b==0
    float s    = tsum[v] / tm + bleed[v] / tmp;
    out_tim[v] = s / (float)(c == 0 ? 1 : c);

    // dy = C[:, ::2] - C[:, 1::2]; diff_y = dy[:,:,::2] + dy[:,:,1::2]
    // dx = C[:, :, ::2] - C[:, :, 1::2]; diff_x = dx[:,1::2] + dx[:,::2]
    out_dx[v] = (float)(c00 - c01 + c10 - c11);
    out_dy[v] = (float)(c00 + c01 - c10 - c11);
}

extern "C" void kernel_launch(void* const* d_in, const int* in_sizes, int n_in,
                              void* d_out, int out_size, void* d_ws, size_t ws_size,
                              hipStream_t stream) {
    const float* ev = (const float*)d_in[0];
    int n = in_sizes[0] / 5;

    unsigned int* ws    = (unsigned int*)d_ws;
    unsigned int* tmaxb = ws;
    int*   cont  = (int*)(ws + 16);
    int*   cnt   = (int*)(ws + 16 + FULL);
    float* tsum  = (float*)(ws + 16 + FULL + HALF);
    float* bleed = (float*)(ws + 16 + FULL + 2 * HALF);
    float* out   = (float*)d_out;

    hipLaunchKernelGGL(k_init, dim3(512), dim3(256), 0, stream, ws);
    hipLaunchKernelGGL(k_events, dim3(2048), dim3(256), 0, stream,
                       ev, n, tmaxb, cont, cnt, tsum, bleed);
    hipLaunchKernelGGL(k_epilogue, dim3((HALF + 255) / 256), dim3(256), 0, stream,
                       tmaxb, cont, cnt, tsum, bleed, out);
}